// Round 17
// baseline (230.774 us; speedup 1.0000x reference)
//
#include <hip/hip_runtime.h>
#include <stdint.h>

typedef float  f32x4  __attribute__((ext_vector_type(4)));
typedef short  s16x4  __attribute__((ext_vector_type(4)));
typedef short  s16x8  __attribute__((ext_vector_type(8)));

#define S_LEN 2048
#define D_K   64
#define NBH   32
#define VT_STRIDE (S_LEN + 32)
#define NTILES_BH 4160   // sum over strips of (strip/2+1)
#define MFMA  __builtin_amdgcn_mfma_f32_16x16x32_bf16

__device__ __forceinline__ short f2bf(float f) {
    uint32_t u = __builtin_bit_cast(uint32_t, f);
    u += 0x7fffu + ((u >> 16) & 1u);           // RNE
    return (short)(u >> 16);
}
__device__ __forceinline__ float bf2f(short s) {
    uint32_t u = ((uint32_t)(uint16_t)s) << 16;
    return __builtin_bit_cast(float, u);
}
__device__ __forceinline__ s16x4 cvt4(float4 f) {
    s16x4 r; r[0] = f2bf(f.x); r[1] = f2bf(f.y); r[2] = f2bf(f.z); r[3] = f2bf(f.w);
    return r;
}
__device__ __forceinline__ s16x8 cat(s16x4 a, s16x4 b) {
    return __builtin_shufflevector(a, b, 0, 1, 2, 3, 4, 5, 6, 7);
}
__device__ __forceinline__ void nt_store4(float* p, f32x4 v) {
    __builtin_nontemporal_store(v, (f32x4*)p);
}

// ---- pre-pass: K -> bf16 FRAG-PERMUTED rows, V -> bf16 transposed, k-permuted ----
__global__ __launch_bounds__(256) void preconv(
    const float* __restrict__ K, const float* __restrict__ V,
    short* __restrict__ Kb, short* __restrict__ VT)
{
    const int bh  = blockIdx.x >> 6;
    const int seg = blockIdx.x & 63;
    const int tid = threadIdx.x;
    const float* Ks = K + ((size_t)bh * S_LEN + seg * 32) * D_K;
    const float* Vs = V + ((size_t)bh * S_LEN + seg * 32) * D_K;
    short* Kd  = Kb + ((size_t)bh * S_LEN + seg * 32) * D_K;
    short* VTd = VT + (size_t)bh * D_K * VT_STRIDE + seg * 32;

    for (int i = tid; i < 512; i += 256) {
        const int r = i >> 4, ci = i & 15;
        float4 f = *(const float4*)(Ks + r * D_K + (ci << 2));
        const int j = ((ci & 3) << 1) + ((ci >> 2) & 1) + ((ci >> 3) << 3);
        *(s16x4*)(Kd + r * D_K + (j << 2)) = cvt4(f);
    }
    for (int i = tid; i < 512; i += 256) {
        const int r = i & 31, c = (i >> 5) << 2;
        float4 f = *(const float4*)(Vs + r * D_K + c);
        const int rp = (((r & 15) >> 2) << 3) + (((r >> 4) & 1) << 2) + (r & 3);
        VTd[(size_t)(c + 0) * VT_STRIDE + rp] = f2bf(f.x);
        VTd[(size_t)(c + 1) * VT_STRIDE + rp] = f2bf(f.y);
        VTd[(size_t)(c + 2) * VT_STRIDE + rp] = f2bf(f.z);
        VTd[(size_t)(c + 3) * VT_STRIDE + rp] = f2bf(f.w);
    }
}

// ================== NEW: score-stash kernel (kills 2nd QK^T) ==================
#define CSTRIDE 66
#define PSTRIDE 257
__global__ __launch_bounds__(256) void attn_stash(
    const float* __restrict__ Q, const short* __restrict__ Kb,
    const short* __restrict__ VT, short* __restrict__ SS,
    float* __restrict__ outC, float* __restrict__ outS)
{
    __shared__ float pstg[16 * PSTRIDE];
    __shared__ float cbuf[4][16][CSTRIDE];
    __shared__ float lbuf[4][16];

    const int tid = threadIdx.x, lane = tid & 63, wv = tid >> 6;
    const int xcd = blockIdx.x & 7;
    const int idx = blockIdx.x >> 3;
    const int bh  = (xcd << 2) + (idx >> 7);
    const int strip = 127 - (idx & 127);         // heavy strips first
    const int q0w = strip << 4;
    const int l15 = lane & 15;
    const int g   = lane >> 4;
    const int d0  = g << 2;
    const int qg  = q0w + l15;

    const short* Kbh = Kb + (size_t)bh * S_LEN * D_K;
    const short* VTh = VT + (size_t)bh * D_K * VT_STRIDE;
    float* outSb = outS + (size_t)bh * S_LEN * S_LEN;
    float* outCb = outC + (size_t)bh * S_LEN * D_K;

    // stash base for this (bh,strip): tile t occupies 512 shorts; lane owns 16B
    const int h2 = strip >> 1;
    const int soff = h2 * (h2 + 1) + (strip & 1) * (h2 + 1);
    short* SSb = SS + ((size_t)bh * NTILES_BH + soff) * 512 + (lane << 3);

    s16x8 qf0, qf1;
    {
        const float4* qp = (const float4*)(Q + ((size_t)bh * S_LEN + qg) * D_K);
        qf0 = cat(cvt4(qp[g]),     cvt4(qp[g + 4]));
        qf1 = cat(cvt4(qp[g + 8]), cvt4(qp[g + 12]));
    }

    const int ntiles = (strip >> 1) + 1;
    const int nfull  = strip >> 1;
    const float scale = 0.125f;

    // ========= phase 1: QK^T once -> bf16 stash + row sums (3-deep pipeline) =========
    float lsum = 0.f;
    {
        auto LD = [&](s16x8& r0, s16x8& r1, s16x8& r2, s16x8& r3, int t) {
            const short* p = Kbh + (((size_t)t << 5) + l15) * D_K + (g << 3);
            r0 = *(const s16x8*)(p);
            r1 = *(const s16x8*)(p + 32);
            r2 = *(const s16x8*)(p + 16 * D_K);
            r3 = *(const s16x8*)(p + 16 * D_K + 32);
        };
        auto SUM = [&](s16x8 r0, s16x8 r1, s16x8 r2, s16x8 r3, int T) {
            f32x4 c0 = {0.f,0.f,0.f,0.f}, c1 = {0.f,0.f,0.f,0.f};
            c0 = MFMA(r0, qf0, c0, 0,0,0);
            c0 = MFMA(r1, qf1, c0, 0,0,0);
            c1 = MFMA(r2, qf0, c1, 0,0,0);
            c1 = MFMA(r3, qf1, c1, 0,0,0);
            s16x8 sf;
            #pragma unroll
            for (int r = 0; r < 4; ++r) { sf[r] = f2bf(c0[r]); sf[4 + r] = f2bf(c1[r]); }
            *(s16x8*)(SSb + (size_t)T * 512) = sf;     // plain store: L2-resident for phase 2
            if (T < nfull) {
                #pragma unroll
                for (int r = 0; r < 4; ++r)
                    lsum += __expf(bf2f(sf[r]) * scale) + __expf(bf2f(sf[4 + r]) * scale);
            } else {
                const int kb0 = (T << 5) + d0;
                #pragma unroll
                for (int r = 0; r < 4; ++r) {
                    if (kb0 + r <= qg)      lsum += __expf(bf2f(sf[r]) * scale);
                    if (kb0 + 16 + r <= qg) lsum += __expf(bf2f(sf[4 + r]) * scale);
                }
            }
        };
        s16x8 A0,A1,A2,A3, B0,B1,B2,B3, C0,C1,C2,C3;
        int t = wv;
        if (t < ntiles) {
            LD(A0,A1,A2,A3, t);
            if (t + 4 < ntiles) LD(B0,B1,B2,B3, t + 4);
            if (t + 8 < ntiles) LD(C0,C1,C2,C3, t + 8);
            for (;;) {
                SUM(A0,A1,A2,A3, t);
                t += 4;
                if (t >= ntiles) break;
                if (t + 8 < ntiles) LD(A0,A1,A2,A3, t + 8);
                SUM(B0,B1,B2,B3, t);
                t += 4;
                if (t >= ntiles) break;
                if (t + 8 < ntiles) LD(B0,B1,B2,B3, t + 8);
                SUM(C0,C1,C2,C3, t);
                t += 4;
                if (t >= ntiles) break;
                if (t + 8 < ntiles) LD(C0,C1,C2,C3, t + 8);
            }
        }
    }
    lsum += __shfl_xor(lsum, 16);
    lsum += __shfl_xor(lsum, 32);
    if (lane < 16) lbuf[wv][l15] = lsum;
    __syncthreads();
    const float rinv = 1.f / (lbuf[0][l15] + lbuf[1][l15] + lbuf[2][l15] + lbuf[3][l15]);

    // ==== phase 2: stash-read -> exp/normalize -> stage + PV; chunked 1KB nt flush ====
    f32x4 ctx0 = {0.f,0.f,0.f,0.f}, ctx1 = ctx0, ctx2 = ctx0, ctx3 = ctx0;
    {
        s16x8 s0, v0[4], s1, v1[4];

        auto LDT = [&](s16x8& ss, s16x8* vv, int t) {
            ss = *(const s16x8*)(SSb + (size_t)t * 512);
            const short* vp = VTh + (size_t)l15 * VT_STRIDE + (t << 5) + (g << 3);
            vv[0] = *(const s16x8*)(vp);
            vv[1] = *(const s16x8*)(vp + 16 * VT_STRIDE);
            vv[2] = *(const s16x8*)(vp + 32 * VT_STRIDE);
            vv[3] = *(const s16x8*)(vp + 48 * VT_STRIDE);
        };
        auto CMPS = [&](s16x8 ss, const s16x8* vv, int T, int tt) {
            f32x4 p0, p1;
            s16x8 pf;
            if (T < nfull) {
                #pragma unroll
                for (int r = 0; r < 4; ++r) {
                    float e0 = __expf(bf2f(ss[r]) * scale) * rinv;
                    float e1 = __expf(bf2f(ss[4 + r]) * scale) * rinv;
                    p0[r] = e0; p1[r] = e1;
                    pf[r] = f2bf(e0); pf[4 + r] = f2bf(e1);
                }
            } else {
                const int kb0 = (T << 5) + d0;
                #pragma unroll
                for (int r = 0; r < 4; ++r) {
                    float e0 = (kb0 + r <= qg)      ? __expf(bf2f(ss[r]) * scale) * rinv : 0.f;
                    float e1 = (kb0 + 16 + r <= qg) ? __expf(bf2f(ss[4 + r]) * scale) * rinv : 0.f;
                    p0[r] = e0; p1[r] = e1;
                    pf[r] = f2bf(e0); pf[4 + r] = f2bf(e1);
                }
            }
            *(f32x4*)&pstg[l15 * PSTRIDE + (tt << 5) + d0]      = p0;
            *(f32x4*)&pstg[l15 * PSTRIDE + (tt << 5) + 16 + d0] = p1;
            ctx0 = MFMA(pf, vv[0], ctx0, 0,0,0);
            ctx1 = MFMA(pf, vv[1], ctx1, 0,0,0);
            ctx2 = MFMA(pf, vv[2], ctx2, 0,0,0);
            ctx3 = MFMA(pf, vv[3], ctx3, 0,0,0);
        };

        if (wv < ntiles)     LDT(s0, v0, wv);
        if (wv + 4 < ntiles) LDT(s1, v1, wv + 4);

        for (int cb = 0; cb < ntiles; cb += 8) {
            const int tA = cb + wv, tB = cb + wv + 4;
            if (tA < ntiles) CMPS(s0, v0, tA, wv);
            const int nA = cb + 8 + wv;
            if (nA < ntiles) LDT(s0, v0, nA);
            if (tB < ntiles) CMPS(s1, v1, tB, wv + 4);
            const int nB = cb + 12 + wv;
            if (nB < ntiles) LDT(s1, v1, nB);
            asm volatile("s_waitcnt lgkmcnt(0)" ::: "memory");
            __builtin_amdgcn_s_barrier();
            const int rem = ntiles - cb;
            const int W = ((rem < 8) ? rem : 8) << 5;
            const size_t gb = (size_t)q0w * S_LEN + ((size_t)cb << 5);
            const int col = lane << 2;
            if (col < W) {
                #pragma unroll
                for (int rr = 0; rr < 16; rr += 4) {
                    const int row = rr + wv;
                    nt_store4(outSb + gb + (size_t)row * S_LEN + col,
                              *(const f32x4*)&pstg[row * PSTRIDE + col]);
                }
            }
            asm volatile("s_waitcnt lgkmcnt(0)" ::: "memory");
            __builtin_amdgcn_s_barrier();
        }
    }

    // zero-fill masked region
    const int kz = ntiles << 5;
    const f32x4 z = {0.f,0.f,0.f,0.f};
    {
        const int c0 = tid << 2;
        for (int r = 0; r < 16; ++r) {
            float* rowp = outSb + (size_t)(q0w + r) * S_LEN;
            for (int k = kz + c0; k < S_LEN; k += 1024)
                *(f32x4*)(rowp + k) = z;
        }
    }

    // combine partial ctx across the 4 waves via LDS
    #pragma unroll
    for (int r = 0; r < 4; ++r) {
        cbuf[wv][d0 + r][ 0 + l15] = ctx0[r];
        cbuf[wv][d0 + r][16 + l15] = ctx1[r];
        cbuf[wv][d0 + r][32 + l15] = ctx2[r];
        cbuf[wv][d0 + r][48 + l15] = ctx3[r];
    }
    __syncthreads();
    {
        const int row = tid >> 4, dbase = (tid & 15) << 2;
        f32x4 acc = *(const f32x4*)&cbuf[0][row][dbase];
        #pragma unroll
        for (int w = 1; w < 4; ++w) {
            f32x4 p = *(const f32x4*)&cbuf[w][row][dbase];
            acc[0] += p[0]; acc[1] += p[1]; acc[2] += p[2]; acc[3] += p[3];
        }
        *(f32x4*)(outCb + (size_t)(q0w + row) * D_K + dbase) = acc;
    }
}

// ================== MID fallback: R16 fused kernel (217us proven) ==================
__global__ __launch_bounds__(256) void attn_fused(
    const float* __restrict__ Q, const short* __restrict__ Kb,
    const short* __restrict__ VT, float* __restrict__ outC,
    float* __restrict__ outS)
{
    __shared__ float pstg[16 * PSTRIDE];
    __shared__ float cbuf[4][16][CSTRIDE];
    __shared__ float lbuf[4][16];

    const int tid = threadIdx.x, lane = tid & 63, wv = tid >> 6;
    const int xcd = blockIdx.x & 7;
    const int idx = blockIdx.x >> 3;
    const int bh  = (xcd << 2) + (idx >> 7);
    const int strip = 127 - (idx & 127);
    const int q0w = strip << 4;
    const int l15 = lane & 15;
    const int g   = lane >> 4;
    const int d0  = g << 2;
    const int qg  = q0w + l15;

    const short* Kbh = Kb + (size_t)bh * S_LEN * D_K;
    const short* VTh = VT + (size_t)bh * D_K * VT_STRIDE;
    float* outSb = outS + (size_t)bh * S_LEN * S_LEN;
    float* outCb = outC + (size_t)bh * S_LEN * D_K;

    s16x8 qf0, qf1;
    {
        const float4* qp = (const float4*)(Q + ((size_t)bh * S_LEN + qg) * D_K);
        qf0 = cat(cvt4(qp[g]),     cvt4(qp[g + 4]));
        qf1 = cat(cvt4(qp[g + 8]), cvt4(qp[g + 12]));
    }

    const int ntiles = (strip >> 1) + 1;
    const int nfull  = strip >> 1;
    const float scale = 0.125f;

    float lsum = 0.f;
    {
        auto LD = [&](s16x8& r0, s16x8& r1, s16x8& r2, s16x8& r3, int t) {
            const short* p = Kbh + (((size_t)t << 5) + l15) * D_K + (g << 3);
            r0 = *(const s16x8*)(p);
            r1 = *(const s16x8*)(p + 32);
            r2 = *(const s16x8*)(p + 16 * D_K);
            r3 = *(const s16x8*)(p + 16 * D_K + 32);
        };
        auto SUM = [&](s16x8 r0, s16x8 r1, s16x8 r2, s16x8 r3, int T) {
            f32x4 c0 = {0.f,0.f,0.f,0.f}, c1 = {0.f,0.f,0.f,0.f};
            c0 = MFMA(r0, qf0, c0, 0,0,0);
            c0 = MFMA(r1, qf1, c0, 0,0,0);
            c1 = MFMA(r2, qf0, c1, 0,0,0);
            c1 = MFMA(r3, qf1, c1, 0,0,0);
            if (T < nfull) {
                #pragma unroll
                for (int r = 0; r < 4; ++r)
                    lsum += __expf(c0[r] * scale) + __expf(c1[r] * scale);
            } else {
                const int kb0 = (T << 5) + d0;
                #pragma unroll
                for (int r = 0; r < 4; ++r) {
                    if (kb0 + r <= qg)      lsum += __expf(c0[r] * scale);
                    if (kb0 + 16 + r <= qg) lsum += __expf(c1[r] * scale);
                }
            }
        };
        s16x8 A0,A1,A2,A3, B0,B1,B2,B3, C0,C1,C2,C3;
        int t = wv;
        if (t < ntiles) {
            LD(A0,A1,A2,A3, t);
            if (t + 4 < ntiles) LD(B0,B1,B2,B3, t + 4);
            if (t + 8 < ntiles) LD(C0,C1,C2,C3, t + 8);
            for (;;) {
                SUM(A0,A1,A2,A3, t);
                t += 4;
                if (t >= ntiles) break;
                if (t + 8 < ntiles) LD(A0,A1,A2,A3, t + 8);
                SUM(B0,B1,B2,B3, t);
                t += 4;
                if (t >= ntiles) break;
                if (t + 8 < ntiles) LD(B0,B1,B2,B3, t + 8);
                SUM(C0,C1,C2,C3, t);
                t += 4;
                if (t >= ntiles) break;
                if (t + 8 < ntiles) LD(C0,C1,C2,C3, t + 8);
            }
        }
    }
    lsum += __shfl_xor(lsum, 16);
    lsum += __shfl_xor(lsum, 32);
    if (lane < 16) lbuf[wv][l15] = lsum;
    __syncthreads();
    const float rinv = 1.f / (lbuf[0][l15] + lbuf[1][l15] + lbuf[2][l15] + lbuf[3][l15]);

    f32x4 ctx0 = {0.f,0.f,0.f,0.f}, ctx1 = ctx0, ctx2 = ctx0, ctx3 = ctx0;
    {
        s16x8 k0[4], v0[4], k1[4], v1[4];
        auto LDK = [&](s16x8* kk, s16x8* vv, int t) {
            const short* kp = Kbh + (((size_t)t << 5) + l15) * D_K + (g << 3);
            kk[0] = *(const s16x8*)(kp);
            kk[1] = *(const s16x8*)(kp + 32);
            kk[2] = *(const s16x8*)(kp + 16 * D_K);
            kk[3] = *(const s16x8*)(kp + 16 * D_K + 32);
            const short* vp = VTh + (size_t)l15 * VT_STRIDE + (t << 5) + (g << 3);
            vv[0] = *(const s16x8*)(vp);
            vv[1] = *(const s16x8*)(vp + 16 * VT_STRIDE);
            vv[2] = *(const s16x8*)(vp + 32 * VT_STRIDE);
            vv[3] = *(const s16x8*)(vp + 48 * VT_STRIDE);
        };
        auto CMPS = [&](const s16x8* kk, const s16x8* vv, int T, int tt) {
            f32x4 c0 = {0.f,0.f,0.f,0.f}, c1 = {0.f,0.f,0.f,0.f};
            c0 = MFMA(kk[0], qf0, c0, 0,0,0);
            c0 = MFMA(kk[1], qf1, c0, 0,0,0);
            c1 = MFMA(kk[2], qf0, c1, 0,0,0);
            c1 = MFMA(kk[3], qf1, c1, 0,0,0);
            f32x4 p0, p1;
            s16x8 pf;
            if (T < nfull) {
                #pragma unroll
                for (int r = 0; r < 4; ++r) {
                    float e0 = __expf(c0[r] * scale) * rinv;
                    float e1 = __expf(c1[r] * scale) * rinv;
                    p0[r] = e0; p1[r] = e1;
                    pf[r] = f2bf(e0); pf[4 + r] = f2bf(e1);
                }
            } else {
                const int kb0 = (T << 5) + d0;
                #pragma unroll
                for (int r = 0; r < 4; ++r) {
                    float e0 = (kb0 + r <= qg)      ? __expf(c0[r] * scale) * rinv : 0.f;
                    float e1 = (kb0 + 16 + r <= qg) ? __expf(c1[r] * scale) * rinv : 0.f;
                    p0[r] = e0; p1[r] = e1;
                    pf[r] = f2bf(e0); pf[4 + r] = f2bf(e1);
                }
            }
            *(f32x4*)&pstg[l15 * PSTRIDE + (tt << 5) + d0]      = p0;
            *(f32x4*)&pstg[l15 * PSTRIDE + (tt << 5) + 16 + d0] = p1;
            ctx0 = MFMA(pf, vv[0], ctx0, 0,0,0);
            ctx1 = MFMA(pf, vv[1], ctx1, 0,0,0);
            ctx2 = MFMA(pf, vv[2], ctx2, 0,0,0);
            ctx3 = MFMA(pf, vv[3], ctx3, 0,0,0);
        };

        if (wv < ntiles)     LDK(k0, v0, wv);
        if (wv + 4 < ntiles) LDK(k1, v1, wv + 4);

        for (int cb = 0; cb < ntiles; cb += 8) {
            const int tA = cb + wv, tB = cb + wv + 4;
            if (tA < ntiles) CMPS(k0, v0, tA, wv);
            const int nA = cb + 8 + wv;
            if (nA < ntiles) LDK(k0, v0, nA);
            if (tB < ntiles) CMPS(k1, v1, tB, wv + 4);
            const int nB = cb + 12 + wv;
            if (nB < ntiles) LDK(k1, v1, nB);
            asm volatile("s_waitcnt lgkmcnt(0)" ::: "memory");
            __builtin_amdgcn_s_barrier();
            const int rem = ntiles - cb;
            const int W = ((rem < 8) ? rem : 8) << 5;
            const size_t gb = (size_t)q0w * S_LEN + ((size_t)cb << 5);
            const int col = lane << 2;
            if (col < W) {
                #pragma unroll
                for (int rr = 0; rr < 16; rr += 4) {
                    const int row = rr + wv;
                    nt_store4(outSb + gb + (size_t)row * S_LEN + col,
                              *(const f32x4*)&pstg[row * PSTRIDE + col]);
                }
            }
            asm volatile("s_waitcnt lgkmcnt(0)" ::: "memory");
            __builtin_amdgcn_s_barrier();
        }
    }

    const int kz = ntiles << 5;
    const f32x4 z = {0.f,0.f,0.f,0.f};
    {
        const int c0 = tid << 2;
        for (int r = 0; r < 16; ++r) {
            float* rowp = outSb + (size_t)(q0w + r) * S_LEN;
            for (int k = kz + c0; k < S_LEN; k += 1024)
                *(f32x4*)(rowp + k) = z;
        }
    }

    #pragma unroll
    for (int r = 0; r < 4; ++r) {
        cbuf[wv][d0 + r][ 0 + l15] = ctx0[r];
        cbuf[wv][d0 + r][16 + l15] = ctx1[r];
        cbuf[wv][d0 + r][32 + l15] = ctx2[r];
        cbuf[wv][d0 + r][48 + l15] = ctx3[r];
    }
    __syncthreads();
    {
        const int row = tid >> 4, dbase = (tid & 15) << 2;
        f32x4 acc = *(const f32x4*)&cbuf[0][row][dbase];
        #pragma unroll
        for (int w = 1; w < 4; ++w) {
            f32x4 p = *(const f32x4*)&cbuf[w][row][dbase];
            acc[0] += p[0]; acc[1] += p[1]; acc[2] += p[2]; acc[3] += p[3];
        }
        *(f32x4*)(outCb + (size_t)(q0w + row) * D_K + dbase) = acc;
    }
}

// ---------------- fallback (R0 kernel, proven) if ws too small ----------------
#define KSTRIDE 68
#define VSTRIDE 36
__global__ __launch_bounds__(256) void attn_causal_fb(
    const float* __restrict__ Q, const float* __restrict__ K,
    const float* __restrict__ V, float* __restrict__ outC,
    float* __restrict__ outS)
{
    __shared__ short Klds[32 * KSTRIDE];
    __shared__ short Vlds[64 * VSTRIDE];
    const int bh = blockIdx.x >> 5, q0 = (blockIdx.x & 31) << 6;
    const int tid = threadIdx.x, lane = tid & 63, wv = tid >> 6;
    const int q0w = q0 + (wv << 4), l15 = lane & 15, d0 = (lane >> 4) << 2;
    const int qg = q0w + l15, qhi = q0w + 15;
    const float* Kb = K + (size_t)bh * S_LEN * D_K;
    const float* Vb = V + (size_t)bh * S_LEN * D_K;
    float* outSb = outS + (size_t)bh * S_LEN * S_LEN;
    float* outCb = outC + (size_t)bh * S_LEN * D_K;
    s16x8 qf0, qf1;
    {
        const float4* qp = (const float4*)(Q + ((size_t)bh * S_LEN + qg) * D_K);
        qf0 = cat(cvt4(qp[d0 >> 2]), cvt4(qp[(d0 + 16) >> 2]));
        qf1 = cat(cvt4(qp[(d0 + 32) >> 2]), cvt4(qp[(d0 + 48) >> 2]));
    }
    const int npairs = (q0 >> 5) + 2;
    const float scale = 0.125f;
    float lsum = 0.f;
    for (int p = 0; p < npairs; ++p) {
        const int k0 = p << 5;
        for (int i = tid; i < 512; i += 256) {
            const int r = i >> 4, c = (i & 15) << 2;
            float4 f = *(const float4*)(Kb + (size_t)(k0 + r) * D_K + c);
            *(s16x4*)&Klds[r * KSTRIDE + c] = cvt4(f);
        }
        __syncthreads();
        if (k0 <= qhi) {
            #pragma unroll
            for (int s = 0; s < 2; ++s) {
                const short* kp = &Klds[(16 * s + l15) * KSTRIDE + d0];
                s16x8 a0 = cat(*(const s16x4*)kp, *(const s16x4*)(kp + 16));
                s16x8 a1 = cat(*(const s16x4*)(kp + 32), *(const s16x4*)(kp + 48));
                f32x4 c1 = {0.f,0.f,0.f,0.f};
                c1 = MFMA(a0, qf0, c1, 0,0,0);
                c1 = MFMA(a1, qf1, c1, 0,0,0);
                const int kbase = k0 + 16 * s + d0;
                #pragma unroll
                for (int r = 0; r < 4; ++r)
                    if (kbase + r <= qg) lsum += __expf(c1[r] * scale);
            }
        }
        __syncthreads();
    }
    lsum += __shfl_xor(lsum, 16);
    lsum += __shfl_xor(lsum, 32);
    const float rinv = 1.f / lsum;
    f32x4 ctx[4] = {{0,0,0,0},{0,0,0,0},{0,0,0,0},{0,0,0,0}};
    for (int p = 0; p < npairs; ++p) {
        const int k0 = p << 5;
        for (int i = tid; i < 512; i += 256) {
            const int r = i >> 4, c = (i & 15) << 2;
            float4 f = *(const float4*)(Kb + (size_t)(k0 + r) * D_K + c);
            *(s16x4*)&Klds[r * KSTRIDE + c] = cvt4(f);
            float4 gg = *(const float4*)(Vb + (size_t)(k0 + r) * D_K + c);
            Vlds[(c + 0) * VSTRIDE + r] = f2bf(gg.x);
            Vlds[(c + 1) * VSTRIDE + r] = f2bf(gg.y);
            Vlds[(c + 2) * VSTRIDE + r] = f2bf(gg.z);
            Vlds[(c + 3) * VSTRIDE + r] = f2bf(gg.w);
        }
        __syncthreads();
        if (k0 <= qhi) {
            s16x8 pf;
            #pragma unroll
            for (int s = 0; s < 2; ++s) {
                const short* kp = &Klds[(16 * s + l15) * KSTRIDE + d0];
                s16x8 a0 = cat(*(const s16x4*)kp, *(const s16x4*)(kp + 16));
                s16x8 a1 = cat(*(const s16x4*)(kp + 32), *(const s16x4*)(kp + 48));
                f32x4 c1 = {0.f,0.f,0.f,0.f};
                c1 = MFMA(a0, qf0, c1, 0,0,0);
                c1 = MFMA(a1, qf1, c1, 0,0,0);
                const int kbase = k0 + 16 * s + d0;
                f32x4 pw;
                #pragma unroll
                for (int r = 0; r < 4; ++r) {
                    float pe = (kbase + r <= qg) ? __expf(c1[r] * scale) * rinv : 0.f;
                    pw[r] = pe;
                    pf[4 * s + r] = f2bf(pe);
                }
                *(f32x4*)(outSb + (size_t)qg * S_LEN + kbase) = pw;
            }
            #pragma unroll
            for (int db = 0; db < 4; ++db) {
                const short* vp = &Vlds[(db * 16 + l15) * VSTRIDE + d0];
                s16x8 b = cat(*(const s16x4*)vp, *(const s16x4*)(vp + 16));
                ctx[db] = MFMA(pf, b, ctx[db], 0,0,0);
            }
        }
        __syncthreads();
    }
    #pragma unroll
    for (int db = 0; db < 4; ++db)
        #pragma unroll
        for (int r = 0; r < 4; ++r)
            outCb[(size_t)(q0w + d0 + r) * D_K + db * 16 + l15] = ctx[db][r];
    const int kz = ((qhi >> 5) + 1) << 5;
    const f32x4 z = {0.f,0.f,0.f,0.f};
    for (int r = 0; r < 16; ++r) {
        float* rowp = outSb + (size_t)(q0w + r) * S_LEN;
        for (int k = kz + (lane << 2); k < S_LEN; k += 256)
            *(f32x4*)(rowp + k) = z;
    }
}

extern "C" void kernel_launch(void* const* d_in, const int* in_sizes, int n_in,
                              void* d_out, int out_size, void* d_ws, size_t ws_size,
                              hipStream_t stream) {
    const float* Q = (const float*)d_in[0];
    const float* K = (const float*)d_in[1];
    const float* V = (const float*)d_in[2];
    float* outC = (float*)d_out;
    float* outS = (float*)d_out + (size_t)NBH * S_LEN * D_K;

    const size_t kb_elems = (size_t)NBH * S_LEN * D_K;
    const size_t vt_elems = (size_t)NBH * D_K * VT_STRIDE;
    const size_t st_elems = (size_t)NBH * NTILES_BH * 512;
    const size_t need_mid  = (kb_elems + vt_elems) * sizeof(short);
    const size_t need_full = need_mid + st_elems * sizeof(short);

    if (ws_size >= need_full) {
        short* Kb = (short*)d_ws;
        short* VT = Kb + kb_elems;
        short* SS = VT + vt_elems;
        preconv<<<dim3(NBH * 64), dim3(256), 0, stream>>>(K, V, Kb, VT);
        attn_stash<<<dim3(4096), dim3(256), 0, stream>>>(Q, Kb, VT, SS, outC, outS);
    } else if (ws_size >= need_mid) {
        short* Kb = (short*)d_ws;
        short* VT = Kb + kb_elems;
        preconv<<<dim3(NBH * 64), dim3(256), 0, stream>>>(K, V, Kb, VT);
        attn_fused<<<dim3(4096), dim3(256), 0, stream>>>(Q, Kb, VT, outC, outS);
    } else {
        attn_causal_fb<<<dim3(1024), dim3(256), 0, stream>>>(Q, K, V, outC, outS);
    }
}

// Round 18
// 209.141 us; speedup vs baseline: 1.1034x; 1.1034x over previous
//
#include <hip/hip_runtime.h>
#include <stdint.h>

typedef float  f32x4  __attribute__((ext_vector_type(4)));
typedef short  s16x4  __attribute__((ext_vector_type(4)));
typedef short  s16x8  __attribute__((ext_vector_type(8)));

#define S_LEN 2048
#define D_K   64
#define NBH   32
#define VT_STRIDE (S_LEN + 32)
#define MFMA  __builtin_amdgcn_mfma_f32_16x16x32_bf16

__device__ __forceinline__ short f2bf(float f) {
    uint32_t u = __builtin_bit_cast(uint32_t, f);
    u += 0x7fffu + ((u >> 16) & 1u);           // RNE
    return (short)(u >> 16);
}
__device__ __forceinline__ s16x4 cvt4(float4 f) {
    s16x4 r; r[0] = f2bf(f.x); r[1] = f2bf(f.y); r[2] = f2bf(f.z); r[3] = f2bf(f.w);
    return r;
}
__device__ __forceinline__ s16x8 cat(s16x4 a, s16x4 b) {
    return __builtin_shufflevector(a, b, 0, 1, 2, 3, 4, 5, 6, 7);
}
__device__ __forceinline__ void nt_store4(float* p, f32x4 v) {
    __builtin_nontemporal_store(v, (f32x4*)p);
}

// ---- pre-pass: K -> bf16 FRAG-PERMUTED rows, V -> bf16 transposed, k-permuted ----
__global__ __launch_bounds__(256) void preconv(
    const float* __restrict__ K, const float* __restrict__ V,
    short* __restrict__ Kb, short* __restrict__ VT)
{
    const int bh  = blockIdx.x >> 6;
    const int seg = blockIdx.x & 63;
    const int tid = threadIdx.x;
    const float* Ks = K + ((size_t)bh * S_LEN + seg * 32) * D_K;
    const float* Vs = V + ((size_t)bh * S_LEN + seg * 32) * D_K;
    short* Kd  = Kb + ((size_t)bh * S_LEN + seg * 32) * D_K;
    short* VTd = VT + (size_t)bh * D_K * VT_STRIDE + seg * 32;

    for (int i = tid; i < 512; i += 256) {
        const int r = i >> 4, ci = i & 15;
        float4 f = *(const float4*)(Ks + r * D_K + (ci << 2));
        const int j = ((ci & 3) << 1) + ((ci >> 2) & 1) + ((ci >> 3) << 3);
        *(s16x4*)(Kd + r * D_K + (j << 2)) = cvt4(f);
    }
    for (int i = tid; i < 512; i += 256) {
        const int r = i & 31, c = (i >> 5) << 2;
        float4 f = *(const float4*)(Vs + r * D_K + c);
        const int rp = (((r & 15) >> 2) << 3) + (((r >> 4) & 1) << 2) + (r & 3);
        VTd[(size_t)(c + 0) * VT_STRIDE + rp] = f2bf(f.x);
        VTd[(size_t)(c + 1) * VT_STRIDE + rp] = f2bf(f.y);
        VTd[(size_t)(c + 2) * VT_STRIDE + rp] = f2bf(f.z);
        VTd[(size_t)(c + 3) * VT_STRIDE + rp] = f2bf(f.w);
    }
}

// ---- fused main: R16 base + 32-tile chunks -> 4KB-contiguous nt flush runs ----
#define PSTRIDE 1025   // odd stride: conflict-free staging banks (R14-proven pattern)
__global__ __launch_bounds__(256) void attn_fused(
    const float* __restrict__ Q, const short* __restrict__ Kb,
    const short* __restrict__ VT, float* __restrict__ outC,
    float* __restrict__ outS)
{
    __shared__ float pstg[16 * PSTRIDE];     // 65.6 KB: chunk staging; reused for combine
    __shared__ float lbuf[4][16];

    const int tid = threadIdx.x, lane = tid & 63, wv = tid >> 6;
    const int xcd = blockIdx.x & 7;
    const int idx = blockIdx.x >> 3;
    const int bh  = (xcd << 2) + (idx >> 7);
    const int strip = 127 - (idx & 127);         // heavy strips first
    const int q0w = strip << 4;
    const int l15 = lane & 15;
    const int g   = lane >> 4;
    const int d0  = g << 2;
    const int qg  = q0w + l15;

    const short* Kbh = Kb + (size_t)bh * S_LEN * D_K;
    const short* VTh = VT + (size_t)bh * D_K * VT_STRIDE;
    float* outSb = outS + (size_t)bh * S_LEN * S_LEN;
    float* outCb = outC + (size_t)bh * S_LEN * D_K;

    s16x8 qf0, qf1;
    {
        const float4* qp = (const float4*)(Q + ((size_t)bh * S_LEN + qg) * D_K);
        qf0 = cat(cvt4(qp[g]),     cvt4(qp[g + 4]));
        qf1 = cat(cvt4(qp[g + 8]), cvt4(qp[g + 12]));
    }

    const int ntiles = (strip >> 1) + 1;
    const int nfull  = strip >> 1;
    const float scale = 0.125f;

    // ================= phase 1: row sums (3-deep rotating pipeline, R16-proven) =================
    float lsum = 0.f;
    {
        auto LD = [&](s16x8& r0, s16x8& r1, s16x8& r2, s16x8& r3, int t) {
            const short* p = Kbh + (((size_t)t << 5) + l15) * D_K + (g << 3);
            r0 = *(const s16x8*)(p);
            r1 = *(const s16x8*)(p + 32);
            r2 = *(const s16x8*)(p + 16 * D_K);
            r3 = *(const s16x8*)(p + 16 * D_K + 32);
        };
        auto SUM = [&](s16x8 r0, s16x8 r1, s16x8 r2, s16x8 r3, int T) {
            f32x4 c0 = {0.f,0.f,0.f,0.f}, c1 = {0.f,0.f,0.f,0.f};
            c0 = MFMA(r0, qf0, c0, 0,0,0);
            c0 = MFMA(r1, qf1, c0, 0,0,0);
            c1 = MFMA(r2, qf0, c1, 0,0,0);
            c1 = MFMA(r3, qf1, c1, 0,0,0);
            if (T < nfull) {
                #pragma unroll
                for (int r = 0; r < 4; ++r)
                    lsum += __expf(c0[r] * scale) + __expf(c1[r] * scale);
            } else {
                const int kb0 = (T << 5) + d0;
                #pragma unroll
                for (int r = 0; r < 4; ++r) {
                    if (kb0 + r <= qg)      lsum += __expf(c0[r] * scale);
                    if (kb0 + 16 + r <= qg) lsum += __expf(c1[r] * scale);
                }
            }
        };
        s16x8 A0,A1,A2,A3, B0,B1,B2,B3, C0,C1,C2,C3;
        int t = wv;
        if (t < ntiles) {
            LD(A0,A1,A2,A3, t);
            if (t + 4 < ntiles) LD(B0,B1,B2,B3, t + 4);
            if (t + 8 < ntiles) LD(C0,C1,C2,C3, t + 8);
            for (;;) {
                SUM(A0,A1,A2,A3, t);
                t += 4;
                if (t >= ntiles) break;
                if (t + 8 < ntiles) LD(A0,A1,A2,A3, t + 8);
                SUM(B0,B1,B2,B3, t);
                t += 4;
                if (t >= ntiles) break;
                if (t + 8 < ntiles) LD(B0,B1,B2,B3, t + 8);
                SUM(C0,C1,C2,C3, t);
                t += 4;
                if (t >= ntiles) break;
                if (t + 8 < ntiles) LD(C0,C1,C2,C3, t + 8);
            }
        }
    }
    lsum += __shfl_xor(lsum, 16);
    lsum += __shfl_xor(lsum, 32);
    if (lane < 16) lbuf[wv][l15] = lsum;
    __syncthreads();
    const float rinv = 1.f / (lbuf[0][l15] + lbuf[1][l15] + lbuf[2][l15] + lbuf[3][l15]);

    // ======== phase 2: 32-tile chunk staging + PV; 4KB-contiguous nt flush ========
    f32x4 ctx0 = {0.f,0.f,0.f,0.f}, ctx1 = ctx0, ctx2 = ctx0, ctx3 = ctx0;
    {
        s16x8 k0[4], v0[4], k1[4], v1[4];

        auto LDK = [&](s16x8* kk, s16x8* vv, int t) {
            const short* kp = Kbh + (((size_t)t << 5) + l15) * D_K + (g << 3);
            kk[0] = *(const s16x8*)(kp);
            kk[1] = *(const s16x8*)(kp + 32);
            kk[2] = *(const s16x8*)(kp + 16 * D_K);
            kk[3] = *(const s16x8*)(kp + 16 * D_K + 32);
            const short* vp = VTh + (size_t)l15 * VT_STRIDE + (t << 5) + (g << 3);
            vv[0] = *(const s16x8*)(vp);
            vv[1] = *(const s16x8*)(vp + 16 * VT_STRIDE);
            vv[2] = *(const s16x8*)(vp + 32 * VT_STRIDE);
            vv[3] = *(const s16x8*)(vp + 48 * VT_STRIDE);
        };
        auto CMPS = [&](const s16x8* kk, const s16x8* vv, int T, int tt) {
            f32x4 c0 = {0.f,0.f,0.f,0.f}, c1 = {0.f,0.f,0.f,0.f};
            c0 = MFMA(kk[0], qf0, c0, 0,0,0);
            c0 = MFMA(kk[1], qf1, c0, 0,0,0);
            c1 = MFMA(kk[2], qf0, c1, 0,0,0);
            c1 = MFMA(kk[3], qf1, c1, 0,0,0);
            f32x4 p0, p1;
            s16x8 pf;
            if (T < nfull) {
                #pragma unroll
                for (int r = 0; r < 4; ++r) {
                    float e0 = __expf(c0[r] * scale) * rinv;
                    float e1 = __expf(c1[r] * scale) * rinv;
                    p0[r] = e0; p1[r] = e1;
                    pf[r] = f2bf(e0); pf[4 + r] = f2bf(e1);
                }
            } else {
                const int kb0 = (T << 5) + d0;
                #pragma unroll
                for (int r = 0; r < 4; ++r) {
                    float e0 = (kb0 + r <= qg)      ? __expf(c0[r] * scale) * rinv : 0.f;
                    float e1 = (kb0 + 16 + r <= qg) ? __expf(c1[r] * scale) * rinv : 0.f;
                    p0[r] = e0; p1[r] = e1;
                    pf[r] = f2bf(e0); pf[4 + r] = f2bf(e1);
                }
            }
            *(f32x4*)&pstg[l15 * PSTRIDE + (tt << 5) + d0]      = p0;
            *(f32x4*)&pstg[l15 * PSTRIDE + (tt << 5) + 16 + d0] = p1;
            ctx0 = MFMA(pf, vv[0], ctx0, 0,0,0);
            ctx1 = MFMA(pf, vv[1], ctx1, 0,0,0);
            ctx2 = MFMA(pf, vv[2], ctx2, 0,0,0);
            ctx3 = MFMA(pf, vv[3], ctx3, 0,0,0);
        };

        if (wv < ntiles)     LDK(k0, v0, wv);
        if (wv + 4 < ntiles) LDK(k1, v1, wv + 4);

        for (int cb = 0; cb < ntiles; cb += 32) {
            // compute 32 tiles into staging (4 sub-iterations, 2-deep rolling pipeline)
            for (int sb = cb; sb < cb + 32 && sb < ntiles; sb += 8) {
                const int tA = sb + wv, tB = sb + wv + 4;
                if (tA < ntiles) CMPS(k0, v0, tA, tA - cb);
                const int nA = sb + 8 + wv;
                if (nA < ntiles) LDK(k0, v0, nA);
                if (tB < ntiles) CMPS(k1, v1, tB, tB - cb);
                const int nB = sb + 12 + wv;
                if (nB < ntiles) LDK(k1, v1, nB);
            }
            asm volatile("s_waitcnt lgkmcnt(0)" ::: "memory");
            __builtin_amdgcn_s_barrier();
            // flush: each wave owns 4 rows; per row up to 4 sequential 1KB stores = 4KB run
            const int rem = ntiles - cb;
            const int W = ((rem < 32) ? rem : 32) << 5;      // valid cols this chunk
            const size_t gb = (size_t)q0w * S_LEN + ((size_t)cb << 5);
            #pragma unroll
            for (int rr = 0; rr < 4; ++rr) {
                const int row = (rr << 2) + wv;
                for (int c = lane << 2; c < W; c += 256)
                    nt_store4(outSb + gb + (size_t)row * S_LEN + c,
                              *(const f32x4*)&pstg[row * PSTRIDE + c]);
            }
            asm volatile("s_waitcnt lgkmcnt(0)" ::: "memory");
            __builtin_amdgcn_s_barrier();
        }
    }

    // zero-fill masked region (k >= kz), row-sequential 4KB steps (proven ~6 TB/s)
    const int kz = ntiles << 5;
    const f32x4 z = {0.f,0.f,0.f,0.f};
    {
        const int c0 = tid << 2;
        for (int r = 0; r < 16; ++r) {
            float* rowp = outSb + (size_t)(q0w + r) * S_LEN;
            for (int k = kz + c0; k < S_LEN; k += 1024)
                nt_store4(rowp + k, z);
        }
    }

    // combine partial ctx across the 4 waves (reuse pstg as [4][16][66] after barrier)
    __syncthreads();
    {
        float* cb2 = pstg;   // w*(16*66) + r*66 + c
        #pragma unroll
        for (int r = 0; r < 4; ++r) {
            cb2[wv * 1056 + (d0 + r) * 66 +  0 + l15] = ctx0[r];
            cb2[wv * 1056 + (d0 + r) * 66 + 16 + l15] = ctx1[r];
            cb2[wv * 1056 + (d0 + r) * 66 + 32 + l15] = ctx2[r];
            cb2[wv * 1056 + (d0 + r) * 66 + 48 + l15] = ctx3[r];
        }
        __syncthreads();
        const int row = tid >> 4, dbase = (tid & 15) << 2;
        f32x4 acc = *(const f32x4*)&cb2[0 * 1056 + row * 66 + dbase];
        #pragma unroll
        for (int w = 1; w < 4; ++w) {
            f32x4 p = *(const f32x4*)&cb2[w * 1056 + row * 66 + dbase];
            acc[0] += p[0]; acc[1] += p[1]; acc[2] += p[2]; acc[3] += p[3];
        }
        *(f32x4*)(outCb + (size_t)(q0w + row) * D_K + dbase) = acc;
    }
}

// ---------------- fallback (R0 kernel, proven) if ws too small ----------------
#define KSTRIDE 68
#define VSTRIDE 36
__global__ __launch_bounds__(256) void attn_causal_fb(
    const float* __restrict__ Q, const float* __restrict__ K,
    const float* __restrict__ V, float* __restrict__ outC,
    float* __restrict__ outS)
{
    __shared__ short Klds[32 * KSTRIDE];
    __shared__ short Vlds[64 * VSTRIDE];
    const int bh = blockIdx.x >> 5, q0 = (blockIdx.x & 31) << 6;
    const int tid = threadIdx.x, lane = tid & 63, wv = tid >> 6;
    const int q0w = q0 + (wv << 4), l15 = lane & 15, d0 = (lane >> 4) << 2;
    const int qg = q0w + l15, qhi = q0w + 15;
    const float* Kb = K + (size_t)bh * S_LEN * D_K;
    const float* Vb = V + (size_t)bh * S_LEN * D_K;
    float* outSb = outS + (size_t)bh * S_LEN * S_LEN;
    float* outCb = outC + (size_t)bh * S_LEN * D_K;
    s16x8 qf0, qf1;
    {
        const float4* qp = (const float4*)(Q + ((size_t)bh * S_LEN + qg) * D_K);
        qf0 = cat(cvt4(qp[d0 >> 2]), cvt4(qp[(d0 + 16) >> 2]));
        qf1 = cat(cvt4(qp[(d0 + 32) >> 2]), cvt4(qp[(d0 + 48) >> 2]));
    }
    const int npairs = (q0 >> 5) + 2;
    const float scale = 0.125f;
    float lsum = 0.f;
    for (int p = 0; p < npairs; ++p) {
        const int k0 = p << 5;
        for (int i = tid; i < 512; i += 256) {
            const int r = i >> 4, c = (i & 15) << 2;
            float4 f = *(const float4*)(Kb + (size_t)(k0 + r) * D_K + c);
            *(s16x4*)&Klds[r * KSTRIDE + c] = cvt4(f);
        }
        __syncthreads();
        if (k0 <= qhi) {
            #pragma unroll
            for (int s = 0; s < 2; ++s) {
                const short* kp = &Klds[(16 * s + l15) * KSTRIDE + d0];
                s16x8 a0 = cat(*(const s16x4*)kp, *(const s16x4*)(kp + 16));
                s16x8 a1 = cat(*(const s16x4*)(kp + 32), *(const s16x4*)(kp + 48));
                f32x4 c1 = {0.f,0.f,0.f,0.f};
                c1 = MFMA(a0, qf0, c1, 0,0,0);
                c1 = MFMA(a1, qf1, c1, 0,0,0);
                const int kbase = k0 + 16 * s + d0;
                #pragma unroll
                for (int r = 0; r < 4; ++r)
                    if (kbase + r <= qg) lsum += __expf(c1[r] * scale);
            }
        }
        __syncthreads();
    }
    lsum += __shfl_xor(lsum, 16);
    lsum += __shfl_xor(lsum, 32);
    const float rinv = 1.f / lsum;
    f32x4 ctx[4] = {{0,0,0,0},{0,0,0,0},{0,0,0,0},{0,0,0,0}};
    for (int p = 0; p < npairs; ++p) {
        const int k0 = p << 5;
        for (int i = tid; i < 512; i += 256) {
            const int r = i >> 4, c = (i & 15) << 2;
            float4 f = *(const float4*)(Kb + (size_t)(k0 + r) * D_K + c);
            *(s16x4*)&Klds[r * KSTRIDE + c] = cvt4(f);
            float4 gg = *(const float4*)(Vb + (size_t)(k0 + r) * D_K + c);
            Vlds[(c + 0) * VSTRIDE + r] = f2bf(gg.x);
            Vlds[(c + 1) * VSTRIDE + r] = f2bf(gg.y);
            Vlds[(c + 2) * VSTRIDE + r] = f2bf(gg.z);
            Vlds[(c + 3) * VSTRIDE + r] = f2bf(gg.w);
        }
        __syncthreads();
        if (k0 <= qhi) {
            s16x8 pf;
            #pragma unroll
            for (int s = 0; s < 2; ++s) {
                const short* kp = &Klds[(16 * s + l15) * KSTRIDE + d0];
                s16x8 a0 = cat(*(const s16x4*)kp, *(const s16x4*)(kp + 16));
                s16x8 a1 = cat(*(const s16x4*)(kp + 32), *(const s16x4*)(kp + 48));
                f32x4 c1 = {0.f,0.f,0.f,0.f};
                c1 = MFMA(a0, qf0, c1, 0,0,0);
                c1 = MFMA(a1, qf1, c1, 0,0,0);
                const int kbase = k0 + 16 * s + d0;
                f32x4 pw;
                #pragma unroll
                for (int r = 0; r < 4; ++r) {
                    float pe = (kbase + r <= qg) ? __expf(c1[r] * scale) * rinv : 0.f;
                    pw[r] = pe;
                    pf[4 * s + r] = f2bf(pe);
                }
                *(f32x4*)(outSb + (size_t)qg * S_LEN + kbase) = pw;
            }
            #pragma unroll
            for (int db = 0; db < 4; ++db) {
                const short* vp = &Vlds[(db * 16 + l15) * VSTRIDE + d0];
                s16x8 b = cat(*(const s16x4*)vp, *(const s16x4*)(vp + 16));
                ctx[db] = MFMA(pf, b, ctx[db], 0,0,0);
            }
        }
        __syncthreads();
    }
    #pragma unroll
    for (int db = 0; db < 4; ++db)
        #pragma unroll
        for (int r = 0; r < 4; ++r)
            outCb[(size_t)(q0w + d0 + r) * D_K + db * 16 + l15] = ctx[db][r];
    const int kz = ((qhi >> 5) + 1) << 5;
    const f32x4 z = {0.f,0.f,0.f,0.f};
    for (int r = 0; r < 16; ++r) {
        float* rowp = outSb + (size_t)(q0w + r) * S_LEN;
        for (int k = kz + (lane << 2); k < S_LEN; k += 256)
            *(f32x4*)(rowp + k) = z;
    }
}

extern "C" void kernel_launch(void* const* d_in, const int* in_sizes, int n_in,
                              void* d_out, int out_size, void* d_ws, size_t ws_size,
                              hipStream_t stream) {
    const float* Q = (const float*)d_in[0];
    const float* K = (const float*)d_in[1];
    const float* V = (const float*)d_in[2];
    float* outC = (float*)d_out;
    float* outS = (float*)d_out + (size_t)NBH * S_LEN * D_K;

    const size_t kb_elems = (size_t)NBH * S_LEN * D_K;
    const size_t vt_elems = (size_t)NBH * D_K * VT_STRIDE;
    const size_t need = (kb_elems + vt_elems) * sizeof(short);

    if (ws_size >= need) {
        short* Kb = (short*)d_ws;
        short* VT = Kb + kb_elems;
        preconv<<<dim3(NBH * 64), dim3(256), 0, stream>>>(K, V, Kb, VT);
        attn_fused<<<dim3(4096), dim3(256), 0, stream>>>(Q, Kb, VT, outC, outS);
    } else {
        attn_causal_fb<<<dim3(1024), dim3(256), 0, stream>>>(Q, K, V, outC, outS);
    }
}

// Round 19
// 157.086 us; speedup vs baseline: 1.4691x; 1.3314x over previous
//
#include <hip/hip_runtime.h>
#include <stdint.h>

typedef float  f32x4  __attribute__((ext_vector_type(4)));
typedef short  s16x4  __attribute__((ext_vector_type(4)));
typedef short  s16x8  __attribute__((ext_vector_type(8)));

#define S_LEN 2048
#define D_K   64
#define NBH   32
#define VT_STRIDE (S_LEN + 32)
#define MFMA  __builtin_amdgcn_mfma_f32_16x16x32_bf16

__device__ __forceinline__ short f2bf(float f) {
    uint32_t u = __builtin_bit_cast(uint32_t, f);
    u += 0x7fffu + ((u >> 16) & 1u);           // RNE
    return (short)(u >> 16);
}
__device__ __forceinline__ s16x4 cvt4(float4 f) {
    s16x4 r; r[0] = f2bf(f.x); r[1] = f2bf(f.y); r[2] = f2bf(f.z); r[3] = f2bf(f.w);
    return r;
}
__device__ __forceinline__ s16x8 cat(s16x4 a, s16x4 b) {
    return __builtin_shufflevector(a, b, 0, 1, 2, 3, 4, 5, 6, 7);
}
__device__ __forceinline__ void nt_store4(float* p, f32x4 v) {
    __builtin_nontemporal_store(v, (f32x4*)p);
}

// ---- pre-pass: K -> bf16 FRAG-PERMUTED rows, V -> bf16 transposed, k-permuted ----
__global__ __launch_bounds__(256) void preconv(
    const float* __restrict__ K, const float* __restrict__ V,
    short* __restrict__ Kb, short* __restrict__ VT)
{
    const int bh  = blockIdx.x >> 6;
    const int seg = blockIdx.x & 63;
    const int tid = threadIdx.x;
    const float* Ks = K + ((size_t)bh * S_LEN + seg * 32) * D_K;
    const float* Vs = V + ((size_t)bh * S_LEN + seg * 32) * D_K;
    short* Kd  = Kb + ((size_t)bh * S_LEN + seg * 32) * D_K;
    short* VTd = VT + (size_t)bh * D_K * VT_STRIDE + seg * 32;

    for (int i = tid; i < 512; i += 256) {
        const int r = i >> 4, ci = i & 15;
        float4 f = *(const float4*)(Ks + r * D_K + (ci << 2));
        const int j = ((ci & 3) << 1) + ((ci >> 2) & 1) + ((ci >> 3) << 3);
        *(s16x4*)(Kd + r * D_K + (j << 2)) = cvt4(f);
    }
    for (int i = tid; i < 512; i += 256) {
        const int r = i & 31, c = (i >> 5) << 2;
        float4 f = *(const float4*)(Vs + r * D_K + c);
        const int rp = (((r & 15) >> 2) << 3) + (((r >> 4) & 1) << 2) + (r & 3);
        VTd[(size_t)(c + 0) * VT_STRIDE + rp] = f2bf(f.x);
        VTd[(size_t)(c + 1) * VT_STRIDE + rp] = f2bf(f.y);
        VTd[(size_t)(c + 2) * VT_STRIDE + rp] = f2bf(f.z);
        VTd[(size_t)(c + 3) * VT_STRIDE + rp] = f2bf(f.w);
    }
}

// ---- paired-strip fused kernel: strips (2j, 2j+1) share every K/V tile load ----
#define PSTR 517     // odd stride: conflict-free staging (R14/R18-proven pattern)
#define CHUNK 16     // tiles per flush chunk (512 cols)
__global__ __launch_bounds__(256) void attn_pair(
    const float* __restrict__ Q, const short* __restrict__ Kb,
    const short* __restrict__ VT, float* __restrict__ outC,
    float* __restrict__ outS)
{
    __shared__ float pstg[32 * PSTR];        // 66.2 KB: 32 rows (2 strips) x 512 cols
    __shared__ float lbuf[4][32];

    const int tid = threadIdx.x, lane = tid & 63, wv = tid >> 6;
    const int xcd = blockIdx.x & 7;
    const int idx = blockIdx.x >> 3;             // 0..255
    const int bh  = (xcd << 2) + (idx >> 6);     // 0..31
    const int j   = 63 - (idx & 63);             // heavy pairs first
    const int q0  = j << 5;                      // strip a = rows q0..q0+15, b = +16
    const int l15 = lane & 15;
    const int g   = lane >> 4;
    const int d0  = g << 2;
    const int qa  = q0 + l15;                    // strip-a row of this lane

    const short* Kbh = Kb + (size_t)bh * S_LEN * D_K;
    const short* VTh = VT + (size_t)bh * D_K * VT_STRIDE;
    float* outSb = outS + (size_t)bh * S_LEN * S_LEN;
    float* outCb = outC + (size_t)bh * S_LEN * D_K;

    // Q fragments for both strips
    s16x8 qf0a, qf1a, qf0b, qf1b;
    {
        const float4* qp = (const float4*)(Q + ((size_t)bh * S_LEN + qa) * D_K);
        qf0a = cat(cvt4(qp[g]),     cvt4(qp[g + 4]));
        qf1a = cat(cvt4(qp[g + 8]), cvt4(qp[g + 12]));
        const float4* qp2 = (const float4*)(Q + ((size_t)bh * S_LEN + qa + 16) * D_K);
        qf0b = cat(cvt4(qp2[g]),     cvt4(qp2[g + 4]));
        qf1b = cat(cvt4(qp2[g + 8]), cvt4(qp2[g + 12]));
    }

    const int ntiles = j + 1;                    // identical for both strips
    const float scale = 0.125f;

    // ================= phase 1: row sums for both strips (3-deep pipeline) =================
    float la = 0.f, lb = 0.f;
    {
        auto LD = [&](s16x8& r0, s16x8& r1, s16x8& r2, s16x8& r3, int t) {
            const short* p = Kbh + (((size_t)t << 5) + l15) * D_K + (g << 3);
            r0 = *(const s16x8*)(p);
            r1 = *(const s16x8*)(p + 32);
            r2 = *(const s16x8*)(p + 16 * D_K);
            r3 = *(const s16x8*)(p + 16 * D_K + 32);
        };
        auto SUM = [&](s16x8 r0, s16x8 r1, s16x8 r2, s16x8 r3, int T) {
            f32x4 a0 = {0.f,0.f,0.f,0.f}, a1 = a0, b0 = a0, b1 = a0;
            a0 = MFMA(r0, qf0a, a0, 0,0,0);
            a0 = MFMA(r1, qf1a, a0, 0,0,0);
            a1 = MFMA(r2, qf0a, a1, 0,0,0);
            a1 = MFMA(r3, qf1a, a1, 0,0,0);
            b0 = MFMA(r0, qf0b, b0, 0,0,0);
            b0 = MFMA(r1, qf1b, b0, 0,0,0);
            b1 = MFMA(r2, qf0b, b1, 0,0,0);
            b1 = MFMA(r3, qf1b, b1, 0,0,0);
            if (T < j) {
                #pragma unroll
                for (int r = 0; r < 4; ++r) {
                    la += __expf(a0[r] * scale) + __expf(a1[r] * scale);
                    lb += __expf(b0[r] * scale) + __expf(b1[r] * scale);
                }
            } else {      // diagonal tile: a1 fully masked; shared lane condition
                const int kb0 = (T << 5) + d0;
                #pragma unroll
                for (int r = 0; r < 4; ++r) {
                    const bool c = (kb0 + r) <= qa;
                    if (c) la += __expf(a0[r] * scale);
                    lb += __expf(b0[r] * scale);
                    if (c) lb += __expf(b1[r] * scale);
                }
            }
        };
        s16x8 A0,A1,A2,A3, B0,B1,B2,B3, C0,C1,C2,C3;
        int t = wv;
        if (t < ntiles) {
            LD(A0,A1,A2,A3, t);
            if (t + 4 < ntiles) LD(B0,B1,B2,B3, t + 4);
            if (t + 8 < ntiles) LD(C0,C1,C2,C3, t + 8);
            for (;;) {
                SUM(A0,A1,A2,A3, t);
                t += 4;
                if (t >= ntiles) break;
                if (t + 8 < ntiles) LD(A0,A1,A2,A3, t + 8);
                SUM(B0,B1,B2,B3, t);
                t += 4;
                if (t >= ntiles) break;
                if (t + 8 < ntiles) LD(B0,B1,B2,B3, t + 8);
                SUM(C0,C1,C2,C3, t);
                t += 4;
                if (t >= ntiles) break;
                if (t + 8 < ntiles) LD(C0,C1,C2,C3, t + 8);
            }
        }
    }
    la += __shfl_xor(la, 16); la += __shfl_xor(la, 32);
    lb += __shfl_xor(lb, 16); lb += __shfl_xor(lb, 32);
    if (lane < 16) { lbuf[wv][l15] = la; lbuf[wv][16 + l15] = lb; }
    __syncthreads();
    const float rinva = 1.f / (lbuf[0][l15] + lbuf[1][l15] + lbuf[2][l15] + lbuf[3][l15]);
    const float rinvb = 1.f / (lbuf[0][16 + l15] + lbuf[1][16 + l15]
                             + lbuf[2][16 + l15] + lbuf[3][16 + l15]);

    // ===== phase 2: shared K/V loads -> P for both strips + PV; chunked nt flush =====
    f32x4 cxa0 = {0.f,0.f,0.f,0.f}, cxa1 = cxa0, cxa2 = cxa0, cxa3 = cxa0;
    f32x4 cxb0 = cxa0, cxb1 = cxa0, cxb2 = cxa0, cxb3 = cxa0;
    {
        s16x8 k0[4], v0[4], k1[4], v1[4];

        auto LDK = [&](s16x8* kk, s16x8* vv, int t) {
            const short* kp = Kbh + (((size_t)t << 5) + l15) * D_K + (g << 3);
            kk[0] = *(const s16x8*)(kp);
            kk[1] = *(const s16x8*)(kp + 32);
            kk[2] = *(const s16x8*)(kp + 16 * D_K);
            kk[3] = *(const s16x8*)(kp + 16 * D_K + 32);
            const short* vp = VTh + (size_t)l15 * VT_STRIDE + (t << 5) + (g << 3);
            vv[0] = *(const s16x8*)(vp);
            vv[1] = *(const s16x8*)(vp + 16 * VT_STRIDE);
            vv[2] = *(const s16x8*)(vp + 32 * VT_STRIDE);
            vv[3] = *(const s16x8*)(vp + 48 * VT_STRIDE);
        };
        auto CMPS = [&](const s16x8* kk, const s16x8* vv, int T, int tt) {
            f32x4 a0 = {0.f,0.f,0.f,0.f}, a1 = a0, b0 = a0, b1 = a0;
            a0 = MFMA(kk[0], qf0a, a0, 0,0,0);
            a0 = MFMA(kk[1], qf1a, a0, 0,0,0);
            a1 = MFMA(kk[2], qf0a, a1, 0,0,0);
            a1 = MFMA(kk[3], qf1a, a1, 0,0,0);
            b0 = MFMA(kk[0], qf0b, b0, 0,0,0);
            b0 = MFMA(kk[1], qf1b, b0, 0,0,0);
            b1 = MFMA(kk[2], qf0b, b1, 0,0,0);
            b1 = MFMA(kk[3], qf1b, b1, 0,0,0);
            f32x4 pa0, pa1, pb0, pb1;
            s16x8 pfa, pfb;
            if (T < j) {
                #pragma unroll
                for (int r = 0; r < 4; ++r) {
                    float ea0 = __expf(a0[r] * scale) * rinva;
                    float ea1 = __expf(a1[r] * scale) * rinva;
                    float eb0 = __expf(b0[r] * scale) * rinvb;
                    float eb1 = __expf(b1[r] * scale) * rinvb;
                    pa0[r] = ea0; pa1[r] = ea1; pb0[r] = eb0; pb1[r] = eb1;
                    pfa[r] = f2bf(ea0); pfa[4 + r] = f2bf(ea1);
                    pfb[r] = f2bf(eb0); pfb[4 + r] = f2bf(eb1);
                }
            } else {      // diagonal: a1 = 0; shared condition for a0/b1
                const int kb0 = (T << 5) + d0;
                #pragma unroll
                for (int r = 0; r < 4; ++r) {
                    const bool c = (kb0 + r) <= qa;
                    float ea0 = c ? __expf(a0[r] * scale) * rinva : 0.f;
                    float eb0 = __expf(b0[r] * scale) * rinvb;
                    float eb1 = c ? __expf(b1[r] * scale) * rinvb : 0.f;
                    pa0[r] = ea0; pa1[r] = 0.f; pb0[r] = eb0; pb1[r] = eb1;
                    pfa[r] = f2bf(ea0); pfa[4 + r] = 0;
                    pfb[r] = f2bf(eb0); pfb[4 + r] = f2bf(eb1);
                }
            }
            float* sa = &pstg[l15 * PSTR + (tt << 5) + d0];
            float* sb = &pstg[(16 + l15) * PSTR + (tt << 5) + d0];
            *(f32x4*)(sa)      = pa0;
            *(f32x4*)(sa + 16) = pa1;
            *(f32x4*)(sb)      = pb0;
            *(f32x4*)(sb + 16) = pb1;
            cxa0 = MFMA(pfa, vv[0], cxa0, 0,0,0);
            cxa1 = MFMA(pfa, vv[1], cxa1, 0,0,0);
            cxa2 = MFMA(pfa, vv[2], cxa2, 0,0,0);
            cxa3 = MFMA(pfa, vv[3], cxa3, 0,0,0);
            cxb0 = MFMA(pfb, vv[0], cxb0, 0,0,0);
            cxb1 = MFMA(pfb, vv[1], cxb1, 0,0,0);
            cxb2 = MFMA(pfb, vv[2], cxb2, 0,0,0);
            cxb3 = MFMA(pfb, vv[3], cxb3, 0,0,0);
        };

        if (wv < ntiles)     LDK(k0, v0, wv);
        if (wv + 4 < ntiles) LDK(k1, v1, wv + 4);

        for (int cb = 0; cb < ntiles; cb += CHUNK) {
            for (int sb = cb; sb < cb + CHUNK && sb < ntiles; sb += 8) {
                const int tA = sb + wv, tB = sb + wv + 4;
                if (tA < ntiles) CMPS(k0, v0, tA, tA - cb);
                const int nA = sb + 8 + wv;
                if (nA < ntiles) LDK(k0, v0, nA);
                if (tB < ntiles) CMPS(k1, v1, tB, tB - cb);
                const int nB = sb + 12 + wv;
                if (nB < ntiles) LDK(k1, v1, nB);
            }
            asm volatile("s_waitcnt lgkmcnt(0)" ::: "memory");
            __builtin_amdgcn_s_barrier();
            // flush 32 rows; each wave owns 8 rows, 2x1KB sequential per row
            const int rem = ntiles - cb;
            const int W = ((rem < CHUNK) ? rem : CHUNK) << 5;
            const size_t gb = (size_t)q0 * S_LEN + ((size_t)cb << 5);
            #pragma unroll
            for (int rr = 0; rr < 8; ++rr) {
                const int row = (rr << 2) + wv;                  // 0..31
                for (int c = lane << 2; c < W; c += 256)
                    nt_store4(outSb + gb + (size_t)row * S_LEN + c,
                              *(const f32x4*)&pstg[row * PSTR + c]);
            }
            asm volatile("s_waitcnt lgkmcnt(0)" ::: "memory");
            __builtin_amdgcn_s_barrier();
        }
    }

    // zero-fill masked region for all 32 rows
    const int kz = ntiles << 5;
    const f32x4 z = {0.f,0.f,0.f,0.f};
    {
        const int c0 = tid << 2;
        for (int r = 0; r < 32; ++r) {
            float* rowp = outSb + (size_t)(q0 + r) * S_LEN;
            for (int k = kz + c0; k < S_LEN; k += 1024)
                nt_store4(rowp + k, z);
        }
    }

    // combine partial ctx across the 4 waves (reuse pstg as [4][32][66])
    __syncthreads();
    {
        float* cb2 = pstg;
        #pragma unroll
        for (int r = 0; r < 4; ++r) {
            cb2[wv * 2112 + (d0 + r) * 66 +  0 + l15] = cxa0[r];
            cb2[wv * 2112 + (d0 + r) * 66 + 16 + l15] = cxa1[r];
            cb2[wv * 2112 + (d0 + r) * 66 + 32 + l15] = cxa2[r];
            cb2[wv * 2112 + (d0 + r) * 66 + 48 + l15] = cxa3[r];
            cb2[wv * 2112 + (16 + d0 + r) * 66 +  0 + l15] = cxb0[r];
            cb2[wv * 2112 + (16 + d0 + r) * 66 + 16 + l15] = cxb1[r];
            cb2[wv * 2112 + (16 + d0 + r) * 66 + 32 + l15] = cxb2[r];
            cb2[wv * 2112 + (16 + d0 + r) * 66 + 48 + l15] = cxb3[r];
        }
        __syncthreads();
        const int dbase = (tid & 15) << 2;
        for (int rr = tid >> 4; rr < 32; rr += 16) {
            f32x4 acc = *(const f32x4*)&cb2[0 * 2112 + rr * 66 + dbase];
            #pragma unroll
            for (int w = 1; w < 4; ++w) {
                f32x4 p = *(const f32x4*)&cb2[w * 2112 + rr * 66 + dbase];
                acc[0] += p[0]; acc[1] += p[1]; acc[2] += p[2]; acc[3] += p[3];
            }
            *(f32x4*)(outCb + (size_t)(q0 + rr) * D_K + dbase) = acc;
        }
    }
}

// ---------------- fallback (R0 kernel, proven) if ws too small ----------------
#define KSTRIDE 68
#define VSTRIDE 36
__global__ __launch_bounds__(256) void attn_causal_fb(
    const float* __restrict__ Q, const float* __restrict__ K,
    const float* __restrict__ V, float* __restrict__ outC,
    float* __restrict__ outS)
{
    __shared__ short Klds[32 * KSTRIDE];
    __shared__ short Vlds[64 * VSTRIDE];
    const int bh = blockIdx.x >> 5, q0 = (blockIdx.x & 31) << 6;
    const int tid = threadIdx.x, lane = tid & 63, wv = tid >> 6;
    const int q0w = q0 + (wv << 4), l15 = lane & 15, d0 = (lane >> 4) << 2;
    const int qg = q0w + l15, qhi = q0w + 15;
    const float* Kb = K + (size_t)bh * S_LEN * D_K;
    const float* Vb = V + (size_t)bh * S_LEN * D_K;
    float* outSb = outS + (size_t)bh * S_LEN * S_LEN;
    float* outCb = outC + (size_t)bh * S_LEN * D_K;
    s16x8 qf0, qf1;
    {
        const float4* qp = (const float4*)(Q + ((size_t)bh * S_LEN + qg) * D_K);
        qf0 = cat(cvt4(qp[d0 >> 2]), cvt4(qp[(d0 + 16) >> 2]));
        qf1 = cat(cvt4(qp[(d0 + 32) >> 2]), cvt4(qp[(d0 + 48) >> 2]));
    }
    const int npairs = (q0 >> 5) + 2;
    const float scale = 0.125f;
    float lsum = 0.f;
    for (int p = 0; p < npairs; ++p) {
        const int k0 = p << 5;
        for (int i = tid; i < 512; i += 256) {
            const int r = i >> 4, c = (i & 15) << 2;
            float4 f = *(const float4*)(Kb + (size_t)(k0 + r) * D_K + c);
            *(s16x4*)&Klds[r * KSTRIDE + c] = cvt4(f);
        }
        __syncthreads();
        if (k0 <= qhi) {
            #pragma unroll
            for (int s = 0; s < 2; ++s) {
                const short* kp = &Klds[(16 * s + l15) * KSTRIDE + d0];
                s16x8 a0 = cat(*(const s16x4*)kp, *(const s16x4*)(kp + 16));
                s16x8 a1 = cat(*(const s16x4*)(kp + 32), *(const s16x4*)(kp + 48));
                f32x4 c1 = {0.f,0.f,0.f,0.f};
                c1 = MFMA(a0, qf0, c1, 0,0,0);
                c1 = MFMA(a1, qf1, c1, 0,0,0);
                const int kbase = k0 + 16 * s + d0;
                #pragma unroll
                for (int r = 0; r < 4; ++r)
                    if (kbase + r <= qg) lsum += __expf(c1[r] * scale);
            }
        }
        __syncthreads();
    }
    lsum += __shfl_xor(lsum, 16);
    lsum += __shfl_xor(lsum, 32);
    const float rinv = 1.f / lsum;
    f32x4 ctx[4] = {{0,0,0,0},{0,0,0,0},{0,0,0,0},{0,0,0,0}};
    for (int p = 0; p < npairs; ++p) {
        const int k0 = p << 5;
        for (int i = tid; i < 512; i += 256) {
            const int r = i >> 4, c = (i & 15) << 2;
            float4 f = *(const float4*)(Kb + (size_t)(k0 + r) * D_K + c);
            *(s16x4*)&Klds[r * KSTRIDE + c] = cvt4(f);
            float4 gg = *(const float4*)(Vb + (size_t)(k0 + r) * D_K + c);
            Vlds[(c + 0) * VSTRIDE + r] = f2bf(gg.x);
            Vlds[(c + 1) * VSTRIDE + r] = f2bf(gg.y);
            Vlds[(c + 2) * VSTRIDE + r] = f2bf(gg.z);
            Vlds[(c + 3) * VSTRIDE + r] = f2bf(gg.w);
        }
        __syncthreads();
        if (k0 <= qhi) {
            s16x8 pf;
            #pragma unroll
            for (int s = 0; s < 2; ++s) {
                const short* kp = &Klds[(16 * s + l15) * KSTRIDE + d0];
                s16x8 a0 = cat(*(const s16x4*)kp, *(const s16x4*)(kp + 16));
                s16x8 a1 = cat(*(const s16x4*)(kp + 32), *(const s16x4*)(kp + 48));
                f32x4 c1 = {0.f,0.f,0.f,0.f};
                c1 = MFMA(a0, qf0, c1, 0,0,0);
                c1 = MFMA(a1, qf1, c1, 0,0,0);
                const int kbase = k0 + 16 * s + d0;
                f32x4 pw;
                #pragma unroll
                for (int r = 0; r < 4; ++r) {
                    float pe = (kbase + r <= qg) ? __expf(c1[r] * scale) * rinv : 0.f;
                    pw[r] = pe;
                    pf[4 * s + r] = f2bf(pe);
                }
                *(f32x4*)(outSb + (size_t)qg * S_LEN + kbase) = pw;
            }
            #pragma unroll
            for (int db = 0; db < 4; ++db) {
                const short* vp = &Vlds[(db * 16 + l15) * VSTRIDE + d0];
                s16x8 b = cat(*(const s16x4*)vp, *(const s16x4*)(vp + 16));
                ctx[db] = MFMA(pf, b, ctx[db], 0,0,0);
            }
        }
        __syncthreads();
    }
    #pragma unroll
    for (int db = 0; db < 4; ++db)
        #pragma unroll
        for (int r = 0; r < 4; ++r)
            outCb[(size_t)(q0w + d0 + r) * D_K + db * 16 + l15] = ctx[db][r];
    const int kz = ((qhi >> 5) + 1) << 5;
    const f32x4 z = {0.f,0.f,0.f,0.f};
    for (int r = 0; r < 16; ++r) {
        float* rowp = outSb + (size_t)(q0w + r) * S_LEN;
        for (int k = kz + (lane << 2); k < S_LEN; k += 256)
            *(f32x4*)(rowp + k) = z;
    }
}

extern "C" void kernel_launch(void* const* d_in, const int* in_sizes, int n_in,
                              void* d_out, int out_size, void* d_ws, size_t ws_size,
                              hipStream_t stream) {
    const float* Q = (const float*)d_in[0];
    const float* K = (const float*)d_in[1];
    const float* V = (const float*)d_in[2];
    float* outC = (float*)d_out;
    float* outS = (float*)d_out + (size_t)NBH * S_LEN * D_K;

    const size_t kb_elems = (size_t)NBH * S_LEN * D_K;
    const size_t vt_elems = (size_t)NBH * D_K * VT_STRIDE;
    const size_t need = (kb_elems + vt_elems) * sizeof(short);

    if (ws_size >= need) {
        short* Kb = (short*)d_ws;
        short* VT = Kb + kb_elems;
        preconv<<<dim3(NBH * 64), dim3(256), 0, stream>>>(K, V, Kb, VT);
        attn_pair<<<dim3(2048), dim3(256), 0, stream>>>(Q, Kb, VT, outC, outS);
    } else {
        attn_causal_fb<<<dim3(1024), dim3(256), 0, stream>>>(Q, K, V, outC, outS);
    }
}